// Round 11
// baseline (265.993 us; speedup 1.0000x reference)
//
#include <hip/hip_runtime.h>
#include <stdint.h>

#define IN_F   4096
#define OUT_F  4096
#define BATCHN 8192
#define BK     64
#define NTK    (IN_F / BK)   // 64 K-tiles

using f32x4  = __attribute__((ext_vector_type(4))) float;
using i32x4  = __attribute__((ext_vector_type(4))) int;
using i32x16 = __attribute__((ext_vector_type(16))) int;
using u32x2  = __attribute__((ext_vector_type(2))) unsigned int;
using u32x4  = __attribute__((ext_vector_type(4))) unsigned int;

__device__ __forceinline__ void stg(const int8_t* src, char* sm, int dstoff) {
    __builtin_amdgcn_global_load_lds(
        (const __attribute__((address_space(1))) void*)src,
        (__attribute__((address_space(3))) void*)(sm + dstoff), 16, 0, 0);
}

__device__ __forceinline__ unsigned pack4(int a, int b, int c, int d) {
    return (unsigned)(a & 255) | ((unsigned)(b & 255) << 8) |
           ((unsigned)(c & 255) << 16) | ((unsigned)(d & 255) << 24);
}
__device__ __forceinline__ int q8(float v, float s) {
    int q = __float2int_rn(v * s);
    return q > 127 ? 127 : (q < -127 ? -127 : q);
}

// ---------------------------------------------------------------------------
// Fused prep (unchanged, proven):
//  [0,8192): W quant wq=round(hw[idx]*xi*8128) -> i8; [8192,16384): x row
//  quant -> i8 + rowmul; [16384,16400): bias.
// ---------------------------------------------------------------------------
__global__ __launch_bounds__(256) void prep(const float* __restrict__ hw,
                                            const float* __restrict__ xiW,
                                            const int*   __restrict__ idxW,
                                            u32x2* __restrict__ Wq,
                                            const float* __restrict__ x,
                                            u32x4* __restrict__ Xq,
                                            float* __restrict__ rowmul,
                                            const float* __restrict__ hb,
                                            const float* __restrict__ xiB,
                                            const int*   __restrict__ idxB,
                                            float* __restrict__ bias) {
    __shared__ float wm[4];
    const int b   = blockIdx.x;
    const int tid = threadIdx.x;
    if (b < 8192) {
        size_t t = (size_t)b * 256 + tid;
        size_t base = t * 8;
        i32x4 i0 = *(const i32x4*)(idxW + base);
        i32x4 i1 = *(const i32x4*)(idxW + base + 4);
        f32x4 s0 = *(const f32x4*)(xiW + base);
        f32x4 s1 = *(const f32x4*)(xiW + base + 4);
        const float SW = 8128.0f;  // 127*64; |W| < 1/64 exactly -> fits i8
        int a0 = q8(hw[i0[0]] * s0[0], SW);
        int a1 = q8(hw[i0[1]] * s0[1], SW);
        int a2 = q8(hw[i0[2]] * s0[2], SW);
        int a3 = q8(hw[i0[3]] * s0[3], SW);
        int a4 = q8(hw[i1[0]] * s1[0], SW);
        int a5 = q8(hw[i1[1]] * s1[1], SW);
        int a6 = q8(hw[i1[2]] * s1[2], SW);
        int a7 = q8(hw[i1[3]] * s1[3], SW);
        u32x2 o;
        o[0] = pack4(a0, a1, a2, a3);
        o[1] = pack4(a4, a5, a6, a7);
        Wq[t] = o;
    } else if (b < 16384) {
        const int row = b - 8192;
        const float* xr = x + (size_t)row * IN_F + tid * 16;
        f32x4 v0 = *(const f32x4*)(xr);
        f32x4 v1 = *(const f32x4*)(xr + 4);
        f32x4 v2 = *(const f32x4*)(xr + 8);
        f32x4 v3 = *(const f32x4*)(xr + 12);
        float mx = 0.f;
#pragma unroll
        for (int j = 0; j < 4; ++j) {
            mx = fmaxf(mx, fmaxf(fabsf(v0[j]), fabsf(v1[j])));
            mx = fmaxf(mx, fmaxf(fabsf(v2[j]), fabsf(v3[j])));
        }
#pragma unroll
        for (int m = 32; m >= 1; m >>= 1) mx = fmaxf(mx, __shfl_xor(mx, m));
        if ((tid & 63) == 0) wm[tid >> 6] = mx;
        __syncthreads();
        mx = fmaxf(fmaxf(wm[0], wm[1]), fmaxf(wm[2], wm[3]));
        mx = fmaxf(mx, 1e-8f);
        const float s = 127.0f / mx;
        u32x4 o;
        o[0] = pack4(q8(v0[0], s), q8(v0[1], s), q8(v0[2], s), q8(v0[3], s));
        o[1] = pack4(q8(v1[0], s), q8(v1[1], s), q8(v1[2], s), q8(v1[3], s));
        o[2] = pack4(q8(v2[0], s), q8(v2[1], s), q8(v2[2], s), q8(v2[3], s));
        o[3] = pack4(q8(v3[0], s), q8(v3[1], s), q8(v3[2], s), q8(v3[3], s));
        Xq[(size_t)row * 256 + tid] = o;
        if (tid == 0) rowmul[row] = mx / (127.0f * 8128.0f);
    } else {
        int o = (b - 16384) * 256 + tid;
        if (o < OUT_F) bias[o] = hb[idxB[o]] * xiB[o];
    }
}

// ---------------------------------------------------------------------------
// i8 GEMM, 256x256 block, BK=64, 8 waves (2x4) of 128x64, 1 barrier/K-tile.
// MFMA: mfma_i32_32x32x32_i8 (4404 TOPS, +12% vs 16x16x64's 3944; half the
// instruction count). Per wave per K-tile: 12 ds_read_b128 + 16 MFMA.
// Frags: A 4 x (32 rows), B 2 x (32 cols), k-slices 2 x (K=32).
// Lane map (A and B identical -> k-permutation invariant): row = lane&31,
// 16B k-chunk = (lane>>5) + 2*ks. Swizzle phys = chunk ^ ((row>>1)&3):
// within every 16-lane group bank base (r&1)*16+((r>>1)&3)*4 is a bijection
// -> exactly 2 lanes/bank = conflict-free (m136).
// Sync/tile: stage T+1 -> other buf at start; vmcnt(0)+lgkm(0)+barrier at
// end (stages landed ~1300 cyc earlier). LDS 2 x 32KB -> 2 blocks/CU.
// C/D (guide-verified, shape-determined): col = lane&31,
// row = (g&3) + 8*(g>>2) + 4*(lane>>5), g in [0,16).
// ---------------------------------------------------------------------------
__global__ __launch_bounds__(512, 2) void gemm_i8(const int8_t* __restrict__ Aq,
                                                  const int8_t* __restrict__ Bq,
                                                  const float*  __restrict__ rowmul,
                                                  const float*  __restrict__ bias,
                                                  float*        __restrict__ C) {
    extern __shared__ char smem[];   // 2 x 32KB
    const int tid  = threadIdx.x;
    const int lane = tid & 63;
    const int wave = tid >> 6;
    const int wr   = wave >> 2;  // 0..1 -> A rows wr*128
    const int wc   = wave & 3;   // 0..3 -> B cols wc*64

    // grid: 32m x 16n = 512 blocks; per-XCD 8x8 region (proven ~197MB FETCH)
    const int bid   = blockIdx.x;
    const int xcd   = bid & 7;
    const int local = bid >> 3;                      // 0..63
    const int m_idx = (xcd & 3) * 8 + (local & 7);   // 0..31
    const int n_idx = (xcd >> 2) * 8 + (local >> 3); // 0..15
    const size_t brow = (size_t)m_idx * 256;
    const size_t bcol = (size_t)n_idx * 256;

    // staging: thread t -> row r0=t>>2 (0..127), slot=t&3; source chunk
    // inverse-swizzled; dest linear t*16. (unchanged, proven 0-conflict)
    const int r0 = tid >> 2;
    const int sc = ((tid & 3) ^ ((r0 >> 1) & 3)) << 4;
    const int8_t* aS0 = Aq + (size_t)(brow + r0)       * IN_F + sc;
    const int8_t* aS1 = Aq + (size_t)(brow + 128 + r0) * IN_F + sc;
    const int8_t* bS0 = Bq + (size_t)(bcol + r0)       * IN_F + sc;
    const int8_t* bS1 = Bq + (size_t)(bcol + 128 + r0) * IN_F + sc;
    const int dT = tid << 4;

    // ds_read (forward swizzle), 32-row frags:
    const int r    = lane & 31;
    const int swzr = (r >> 1) & 3;
    const int pk0  = (((lane >> 5)) ^ swzr) << 4;  // ks=0 phys byte offset
    // ks=1: chunk+2 -> phys = pk0 ^ 32
    const int aRdB = (wr * 128 + r) * 64;                 // + f*2048 + pk
    const int bRdB = 16384 + (wc * 64 + r) * 64;          // + n*2048 + pk

    i32x16 acc[4][2];
#pragma unroll
    for (int f = 0; f < 4; ++f)
#pragma unroll
        for (int n = 0; n < 2; ++n)
#pragma unroll
            for (int g = 0; g < 16; ++g) acc[f][n][g] = 0;

    i32x4 aF[4][2], bF[2][2];

#define SB() __builtin_amdgcn_sched_barrier(0)

    // CURB: current buffer base; stage T+1 -> CURB^32768 at AK elem offset
#define TILE(CURB, STGON, AK, LAST) { \
    if (STGON) { \
        const int sb = (CURB) ^ 32768; \
        stg(aS0 + (AK), smem, sb + dT); \
        stg(aS1 + (AK), smem, sb + 8192 + dT); \
        stg(bS0 + (AK), smem, sb + 16384 + dT); \
        stg(bS1 + (AK), smem, sb + 24576 + dT); \
    } \
    _Pragma("unroll") \
    for (int f = 0; f < 4; ++f) { \
        aF[f][0] = *(const i32x4*)(smem + (CURB) + aRdB + f * 2048 + pk0); \
        aF[f][1] = *(const i32x4*)(smem + (CURB) + aRdB + f * 2048 + (pk0 ^ 32)); \
    } \
    _Pragma("unroll") \
    for (int n = 0; n < 2; ++n) { \
        bF[n][0] = *(const i32x4*)(smem + (CURB) + bRdB + n * 2048 + pk0); \
        bF[n][1] = *(const i32x4*)(smem + (CURB) + bRdB + n * 2048 + (pk0 ^ 32)); \
    } \
    __builtin_amdgcn_s_setprio(1); \
    _Pragma("unroll") \
    for (int ks = 0; ks < 2; ++ks) { \
        _Pragma("unroll") \
        for (int f = 0; f < 4; ++f) { \
            _Pragma("unroll") \
            for (int n = 0; n < 2; ++n) \
                acc[f][n] = __builtin_amdgcn_mfma_i32_32x32x32_i8( \
                    aF[f][ks], bF[n][ks], acc[f][n], 0, 0, 0); \
        } } \
    __builtin_amdgcn_s_setprio(0); \
    if (!(LAST)) { \
        asm volatile("s_waitcnt vmcnt(0) lgkmcnt(0)" ::: "memory"); \
        SB(); \
        __builtin_amdgcn_s_barrier(); \
        SB(); \
    } \
}

    // prologue: stage T0 -> buf0; land; barrier
    stg(aS0, smem, dT);
    stg(aS1, smem, 8192 + dT);
    stg(bS0, smem, 16384 + dT);
    stg(bS1, smem, 24576 + dT);
    asm volatile("s_waitcnt vmcnt(0)" ::: "memory");
    SB();
    __builtin_amdgcn_s_barrier();
    SB();

    // tiles 0..61 (31 x unroll-2), then 62 (stages 63), 63 (bare)
    for (int it = 0; it < 31; ++it) {
        TILE(0,     1, 64,  0);   // tile 2it   -> stages 2it+1 into buf1
        TILE(32768, 1, 128, 0);   // tile 2it+1 -> stages 2it+2 into buf0
        aS0 += 128; aS1 += 128; bS0 += 128; bS1 += 128;
    }
    TILE(0,     1, 64, 0);        // tile 62 -> stages 63 into buf1
    TILE(32768, 0, 0,  1);        // tile 63
#undef TILE
#undef SB

    // epilogue: col = lane&31, row = (g&3) + 8*(g>>2) + 4*(lane>>5)
    const int hi = lane >> 5;
    const int cc = lane & 31;
#pragma unroll
    for (int f = 0; f < 4; ++f) {
        const size_t fbase = brow + wr * 128 + f * 32;
#pragma unroll
        for (int n = 0; n < 2; ++n) {
            const size_t col = bcol + wc * 64 + n * 32 + cc;
            const float bv = bias[col];
#pragma unroll
            for (int g = 0; g < 16; ++g) {
                const size_t row = fbase + (g & 3) + 8 * (g >> 2) + 4 * hi;
                C[row * OUT_F + col] = (float)acc[f][n][g] * rowmul[row] + bv;
            }
        }
    }
}

// ---------------------------------------------------------------------------
extern "C" void kernel_launch(void* const* d_in, const int* in_sizes, int n_in,
                              void* d_out, int out_size, void* d_ws, size_t ws_size,
                              hipStream_t stream) {
    const float* x    = (const float*)d_in[0];
    const float* hw   = (const float*)d_in[1];
    const float* hb   = (const float*)d_in[2];
    const float* xiW  = (const float*)d_in[3];
    const float* xiB  = (const float*)d_in[4];
    const int*   idxW = (const int*)d_in[5];
    const int*   idxB = (const int*)d_in[6];
    float* out = (float*)d_out;

    char* ws = (char*)d_ws;
    int8_t* Wq     = (int8_t*)ws;                                   // 16 MB
    int8_t* Xq     = (int8_t*)(ws + (size_t)16 * 1024 * 1024);      // 32 MB
    float*  rowmul = (float*)(ws + (size_t)48 * 1024 * 1024);       // 32 KB
    float*  bia    = (float*)(ws + (size_t)49 * 1024 * 1024);       // 16 KB

    (void)hipFuncSetAttribute((const void*)gemm_i8,
                              hipFuncAttributeMaxDynamicSharedMemorySize, 65536);

    prep<<<16400, 256, 0, stream>>>(hw, xiW, idxW, (u32x2*)Wq,
                                    x, (u32x4*)Xq, rowmul,
                                    hb, xiB, idxB, bia);
    // 32 m x 16 n = 512 blocks, 512 threads, 64KB dynamic LDS
    gemm_i8<<<512, 512, 65536, stream>>>(Xq, Wq, rowmul, bia, out);
}

// Round 12
// 261.320 us; speedup vs baseline: 1.0179x; 1.0179x over previous
//
#include <hip/hip_runtime.h>
#include <stdint.h>

#define IN_F   4096
#define OUT_F  4096
#define BATCHN 8192
#define BK     64
#define NTK    (IN_F / BK)   // 64 K-tiles

using f32x4 = __attribute__((ext_vector_type(4))) float;
using i32x4 = __attribute__((ext_vector_type(4))) int;
using u32x2 = __attribute__((ext_vector_type(2))) unsigned int;
using u32x4 = __attribute__((ext_vector_type(4))) unsigned int;

__device__ __forceinline__ void stg(const int8_t* src, char* sm, int dstoff) {
    __builtin_amdgcn_global_load_lds(
        (const __attribute__((address_space(1))) void*)src,
        (__attribute__((address_space(3))) void*)(sm + dstoff), 16, 0, 0);
}

__device__ __forceinline__ unsigned pack4(int a, int b, int c, int d) {
    return (unsigned)(a & 255) | ((unsigned)(b & 255) << 8) |
           ((unsigned)(c & 255) << 16) | ((unsigned)(d & 255) << 24);
}
__device__ __forceinline__ int q8(float v, float s) {
    int q = __float2int_rn(v * s);
    return q > 127 ? 127 : (q < -127 ? -127 : q);
}

// ---------------------------------------------------------------------------
// Fused prep (proven):
//  [0,8192): W quant wq=round(hw[idx]*xi*8128) -> i8; [8192,16384): x row
//  quant -> i8 + rowmul; [16384,16400): bias.
// ---------------------------------------------------------------------------
__global__ __launch_bounds__(256) void prep(const float* __restrict__ hw,
                                            const float* __restrict__ xiW,
                                            const int*   __restrict__ idxW,
                                            u32x2* __restrict__ Wq,
                                            const float* __restrict__ x,
                                            u32x4* __restrict__ Xq,
                                            float* __restrict__ rowmul,
                                            const float* __restrict__ hb,
                                            const float* __restrict__ xiB,
                                            const int*   __restrict__ idxB,
                                            float* __restrict__ bias) {
    __shared__ float wm[4];
    const int b   = blockIdx.x;
    const int tid = threadIdx.x;
    if (b < 8192) {
        size_t t = (size_t)b * 256 + tid;
        size_t base = t * 8;
        i32x4 i0 = *(const i32x4*)(idxW + base);
        i32x4 i1 = *(const i32x4*)(idxW + base + 4);
        f32x4 s0 = *(const f32x4*)(xiW + base);
        f32x4 s1 = *(const f32x4*)(xiW + base + 4);
        const float SW = 8128.0f;  // 127*64; |W| < 1/64 exactly -> fits i8
        int a0 = q8(hw[i0[0]] * s0[0], SW);
        int a1 = q8(hw[i0[1]] * s0[1], SW);
        int a2 = q8(hw[i0[2]] * s0[2], SW);
        int a3 = q8(hw[i0[3]] * s0[3], SW);
        int a4 = q8(hw[i1[0]] * s1[0], SW);
        int a5 = q8(hw[i1[1]] * s1[1], SW);
        int a6 = q8(hw[i1[2]] * s1[2], SW);
        int a7 = q8(hw[i1[3]] * s1[3], SW);
        u32x2 o;
        o[0] = pack4(a0, a1, a2, a3);
        o[1] = pack4(a4, a5, a6, a7);
        Wq[t] = o;
    } else if (b < 16384) {
        const int row = b - 8192;
        const float* xr = x + (size_t)row * IN_F + tid * 16;
        f32x4 v0 = *(const f32x4*)(xr);
        f32x4 v1 = *(const f32x4*)(xr + 4);
        f32x4 v2 = *(const f32x4*)(xr + 8);
        f32x4 v3 = *(const f32x4*)(xr + 12);
        float mx = 0.f;
#pragma unroll
        for (int j = 0; j < 4; ++j) {
            mx = fmaxf(mx, fmaxf(fabsf(v0[j]), fabsf(v1[j])));
            mx = fmaxf(mx, fmaxf(fabsf(v2[j]), fabsf(v3[j])));
        }
#pragma unroll
        for (int m = 32; m >= 1; m >>= 1) mx = fmaxf(mx, __shfl_xor(mx, m));
        if ((tid & 63) == 0) wm[tid >> 6] = mx;
        __syncthreads();
        mx = fmaxf(fmaxf(wm[0], wm[1]), fmaxf(wm[2], wm[3]));
        mx = fmaxf(mx, 1e-8f);
        const float s = 127.0f / mx;
        u32x4 o;
        o[0] = pack4(q8(v0[0], s), q8(v0[1], s), q8(v0[2], s), q8(v0[3], s));
        o[1] = pack4(q8(v1[0], s), q8(v1[1], s), q8(v1[2], s), q8(v1[3], s));
        o[2] = pack4(q8(v2[0], s), q8(v2[1], s), q8(v2[2], s), q8(v2[3], s));
        o[3] = pack4(q8(v3[0], s), q8(v3[1], s), q8(v3[2], s), q8(v3[3], s));
        Xq[(size_t)row * 256 + tid] = o;
        if (tid == 0) rowmul[row] = mx / (127.0f * 8128.0f);
    } else {
        int o = (b - 16384) * 256 + tid;
        if (o < OUT_F) bias[o] = hb[idxB[o]] * xiB[o];
    }
}

// ---------------------------------------------------------------------------
// i8 GEMM (round-10 best, reproduced): 256x256 block, BK=64, 8 waves (2x4)
// of 128x64, mfma_i32_16x16x64_i8, 1 barrier/K-tile, 2x32KB LDS.
// Read order tweaked: bF[0..3] + aF[0..1] first, remaining aF interleaved
// with the MFMA m-clusters (first MFMA gated on 5 reads instead of 9).
// Swizzle phys_chunk = c ^ ((row>>1)&3) (0-conflict proven r8), inverse on
// global src, forward on ds_read, linear gload_lds dest.
// Sync/tile: stage T+1 -> other buf at start; vmcnt(0)+lgkm(0)+barrier at
// end (stages landed ~1300 cyc earlier).
// ---------------------------------------------------------------------------
__global__ __launch_bounds__(512, 2) void gemm_i8(const int8_t* __restrict__ Aq,
                                                  const int8_t* __restrict__ Bq,
                                                  const float*  __restrict__ rowmul,
                                                  const float*  __restrict__ bias,
                                                  float*        __restrict__ C) {
    extern __shared__ char smem[];   // 2 x 32KB
    const int tid  = threadIdx.x;
    const int lane = tid & 63;
    const int wave = tid >> 6;
    const int wr   = wave >> 2;  // 0..1 -> A rows wr*128
    const int wc   = wave & 3;   // 0..3 -> B cols wc*64

    // grid: 32m x 16n = 512 blocks; per-XCD 8x8 region
    const int bid   = blockIdx.x;
    const int xcd   = bid & 7;
    const int local = bid >> 3;                      // 0..63
    const int m_idx = (xcd & 3) * 8 + (local & 7);   // 0..31
    const int n_idx = (xcd >> 2) * 8 + (local >> 3); // 0..15
    const size_t brow = (size_t)m_idx * 256;
    const size_t bcol = (size_t)n_idx * 256;

    // staging: thread t -> row r0=t>>2 (0..127), slot=t&3; source chunk
    // inverse-swizzled; dest linear t*16.
    const int r0 = tid >> 2;
    const int sc = ((tid & 3) ^ ((r0 >> 1) & 3)) << 4;
    const int8_t* aS0 = Aq + (size_t)(brow + r0)       * IN_F + sc;
    const int8_t* aS1 = Aq + (size_t)(brow + 128 + r0) * IN_F + sc;
    const int8_t* bS0 = Bq + (size_t)(bcol + r0)       * IN_F + sc;
    const int8_t* bS1 = Bq + (size_t)(bcol + 128 + r0) * IN_F + sc;
    const int dT = tid << 4;

    // ds_read (forward swizzle); frag rows are 64B so pcc independent of m,wr
    const int rrow = lane & 15;
    const int pcc  = (((lane >> 4)) ^ ((rrow >> 1) & 3)) << 4;
    const int aRd  = (wr * 128 + rrow) * 64 + pcc;           // + m*1024
    const int bRd  = 16384 + (wc * 64 + rrow) * 64 + pcc;    // + n*1024

    i32x4 acc[8][4];
#pragma unroll
    for (int m = 0; m < 8; ++m)
#pragma unroll
        for (int n = 0; n < 4; ++n) acc[m][n] = (i32x4){0, 0, 0, 0};

    i32x4 aF[8], bF[4];

#define SB() __builtin_amdgcn_sched_barrier(0)

    // CURB: current buffer base; stage T+1 -> CURB^32768 at AK elem offset
#define TILE(CURB, STGON, AK, LAST) { \
    if (STGON) { \
        const int sb = (CURB) ^ 32768; \
        stg(aS0 + (AK), smem, sb + dT); \
        stg(aS1 + (AK), smem, sb + 8192 + dT); \
        stg(bS0 + (AK), smem, sb + 16384 + dT); \
        stg(bS1 + (AK), smem, sb + 24576 + dT); \
    } \
    _Pragma("unroll") \
    for (int n = 0; n < 4; ++n) \
        bF[n] = *(const i32x4*)(smem + (CURB) + bRd + n * 1024); \
    aF[0] = *(const i32x4*)(smem + (CURB) + aRd); \
    aF[1] = *(const i32x4*)(smem + (CURB) + aRd + 1024); \
    __builtin_amdgcn_s_setprio(1); \
    _Pragma("unroll") \
    for (int m = 0; m < 8; ++m) { \
        if (m < 6) \
            aF[m + 2] = *(const i32x4*)(smem + (CURB) + aRd + (m + 2) * 1024); \
        _Pragma("unroll") \
        for (int n = 0; n < 4; ++n) \
            acc[m][n] = __builtin_amdgcn_mfma_i32_16x16x64_i8( \
                aF[m], bF[n], acc[m][n], 0, 0, 0); \
    } \
    __builtin_amdgcn_s_setprio(0); \
    if (!(LAST)) { \
        asm volatile("s_waitcnt vmcnt(0) lgkmcnt(0)" ::: "memory"); \
        SB(); \
        __builtin_amdgcn_s_barrier(); \
        SB(); \
    } \
}

    // prologue: stage T0 -> buf0; land; barrier
    stg(aS0, smem, dT);
    stg(aS1, smem, 8192 + dT);
    stg(bS0, smem, 16384 + dT);
    stg(bS1, smem, 24576 + dT);
    asm volatile("s_waitcnt vmcnt(0)" ::: "memory");
    SB();
    __builtin_amdgcn_s_barrier();
    SB();

    // tiles 0..61 (31 x unroll-2), then 62 (stages 63), 63 (bare)
    for (int it = 0; it < 31; ++it) {
        TILE(0,     1, 64,  0);   // tile 2it   -> stages 2it+1 into buf1
        TILE(32768, 1, 128, 0);   // tile 2it+1 -> stages 2it+2 into buf0
        aS0 += 128; aS1 += 128; bS0 += 128; bS1 += 128;
    }
    TILE(0,     1, 64, 0);        // tile 62 -> stages 63 into buf1
    TILE(32768, 0, 0,  1);        // tile 63
#undef TILE
#undef SB

    // epilogue: C/D col = lane&15, row = (lane>>4)*4 + j (shape-determined)
    const int crow = (lane >> 4) << 2;
    const int ccol = lane & 15;
#pragma unroll
    for (int m = 0; m < 8; ++m) {
        const size_t rowbase = brow + wr * 128 + m * 16 + crow;
        float rm[4];
#pragma unroll
        for (int j = 0; j < 4; ++j) rm[j] = rowmul[rowbase + j];
#pragma unroll
        for (int n = 0; n < 4; ++n) {
            const size_t col = bcol + wc * 64 + n * 16 + ccol;
            const float bv = bias[col];
            float* cp = C + rowbase * OUT_F + col;
#pragma unroll
            for (int j = 0; j < 4; ++j)
                cp[(size_t)j * OUT_F] = (float)acc[m][n][j] * rm[j] + bv;
        }
    }
}

// ---------------------------------------------------------------------------
extern "C" void kernel_launch(void* const* d_in, const int* in_sizes, int n_in,
                              void* d_out, int out_size, void* d_ws, size_t ws_size,
                              hipStream_t stream) {
    const float* x    = (const float*)d_in[0];
    const float* hw   = (const float*)d_in[1];
    const float* hb   = (const float*)d_in[2];
    const float* xiW  = (const float*)d_in[3];
    const float* xiB  = (const float*)d_in[4];
    const int*   idxW = (const int*)d_in[5];
    const int*   idxB = (const int*)d_in[6];
    float* out = (float*)d_out;

    char* ws = (char*)d_ws;
    int8_t* Wq     = (int8_t*)ws;                                   // 16 MB
    int8_t* Xq     = (int8_t*)(ws + (size_t)16 * 1024 * 1024);      // 32 MB
    float*  rowmul = (float*)(ws + (size_t)48 * 1024 * 1024);       // 32 KB
    float*  bia    = (float*)(ws + (size_t)49 * 1024 * 1024);       // 16 KB

    (void)hipFuncSetAttribute((const void*)gemm_i8,
                              hipFuncAttributeMaxDynamicSharedMemorySize, 65536);

    prep<<<16400, 256, 0, stream>>>(hw, xiW, idxW, (u32x2*)Wq,
                                    x, (u32x4*)Xq, rowmul,
                                    hb, xiB, idxB, bia);
    // 32 m x 16 n = 512 blocks, 512 threads, 64KB dynamic LDS
    gemm_i8<<<512, 512, 65536, stream>>>(Xq, Wq, rowmul, bia, out);
}

// Round 13
// 250.900 us; speedup vs baseline: 1.0602x; 1.0415x over previous
//
#include <hip/hip_runtime.h>
#include <stdint.h>

#define IN_F   4096
#define OUT_F  4096
#define BATCHN 8192
#define BK     64
#define NTK    (IN_F / BK)   // 64 K-tiles

using f32x4 = __attribute__((ext_vector_type(4))) float;
using i32x4 = __attribute__((ext_vector_type(4))) int;
using u32x2 = __attribute__((ext_vector_type(2))) unsigned int;
using u32x4 = __attribute__((ext_vector_type(4))) unsigned int;

__device__ __forceinline__ void stg(const int8_t* src, char* sm, int dstoff) {
    __builtin_amdgcn_global_load_lds(
        (const __attribute__((address_space(1))) void*)src,
        (__attribute__((address_space(3))) void*)(sm + dstoff), 16, 0, 0);
}

__device__ __forceinline__ unsigned pack4(int a, int b, int c, int d) {
    return (unsigned)(a & 255) | ((unsigned)(b & 255) << 8) |
           ((unsigned)(c & 255) << 16) | ((unsigned)(d & 255) << 24);
}
__device__ __forceinline__ int q8(float v, float s) {
    int q = __float2int_rn(v * s);
    return q > 127 ? 127 : (q < -127 ? -127 : q);
}

// ---------------------------------------------------------------------------
// Fused prep (proven):
//  [0,8192): W quant wq=round(hw[idx]*xi*8128) -> i8; [8192,16384): x row
//  quant -> i8 + rowmul; [16384,16400): bias.
// ---------------------------------------------------------------------------
__global__ __launch_bounds__(256) void prep(const float* __restrict__ hw,
                                            const float* __restrict__ xiW,
                                            const int*   __restrict__ idxW,
                                            u32x2* __restrict__ Wq,
                                            const float* __restrict__ x,
                                            u32x4* __restrict__ Xq,
                                            float* __restrict__ rowmul,
                                            const float* __restrict__ hb,
                                            const float* __restrict__ xiB,
                                            const int*   __restrict__ idxB,
                                            float* __restrict__ bias) {
    __shared__ float wm[4];
    const int b   = blockIdx.x;
    const int tid = threadIdx.x;
    if (b < 8192) {
        size_t t = (size_t)b * 256 + tid;
        size_t base = t * 8;
        i32x4 i0 = *(const i32x4*)(idxW + base);
        i32x4 i1 = *(const i32x4*)(idxW + base + 4);
        f32x4 s0 = *(const f32x4*)(xiW + base);
        f32x4 s1 = *(const f32x4*)(xiW + base + 4);
        const float SW = 8128.0f;  // 127*64; |W| < 1/64 exactly -> fits i8
        int a0 = q8(hw[i0[0]] * s0[0], SW);
        int a1 = q8(hw[i0[1]] * s0[1], SW);
        int a2 = q8(hw[i0[2]] * s0[2], SW);
        int a3 = q8(hw[i0[3]] * s0[3], SW);
        int a4 = q8(hw[i1[0]] * s1[0], SW);
        int a5 = q8(hw[i1[1]] * s1[1], SW);
        int a6 = q8(hw[i1[2]] * s1[2], SW);
        int a7 = q8(hw[i1[3]] * s1[3], SW);
        u32x2 o;
        o[0] = pack4(a0, a1, a2, a3);
        o[1] = pack4(a4, a5, a6, a7);
        Wq[t] = o;
    } else if (b < 16384) {
        const int row = b - 8192;
        const float* xr = x + (size_t)row * IN_F + tid * 16;
        f32x4 v0 = *(const f32x4*)(xr);
        f32x4 v1 = *(const f32x4*)(xr + 4);
        f32x4 v2 = *(const f32x4*)(xr + 8);
        f32x4 v3 = *(const f32x4*)(xr + 12);
        float mx = 0.f;
#pragma unroll
        for (int j = 0; j < 4; ++j) {
            mx = fmaxf(mx, fmaxf(fabsf(v0[j]), fabsf(v1[j])));
            mx = fmaxf(mx, fmaxf(fabsf(v2[j]), fabsf(v3[j])));
        }
#pragma unroll
        for (int m = 32; m >= 1; m >>= 1) mx = fmaxf(mx, __shfl_xor(mx, m));
        if ((tid & 63) == 0) wm[tid >> 6] = mx;
        __syncthreads();
        mx = fmaxf(fmaxf(wm[0], wm[1]), fmaxf(wm[2], wm[3]));
        mx = fmaxf(mx, 1e-8f);
        const float s = 127.0f / mx;
        u32x4 o;
        o[0] = pack4(q8(v0[0], s), q8(v0[1], s), q8(v0[2], s), q8(v0[3], s));
        o[1] = pack4(q8(v1[0], s), q8(v1[1], s), q8(v1[2], s), q8(v1[3], s));
        o[2] = pack4(q8(v2[0], s), q8(v2[1], s), q8(v2[2], s), q8(v2[3], s));
        o[3] = pack4(q8(v3[0], s), q8(v3[1], s), q8(v3[2], s), q8(v3[3], s));
        Xq[(size_t)row * 256 + tid] = o;
        if (tid == 0) rowmul[row] = mx / (127.0f * 8128.0f);
    } else {
        int o = (b - 16384) * 256 + tid;
        if (o < OUT_F) bias[o] = hb[idxB[o]] * xiB[o];
    }
}

// ---------------------------------------------------------------------------
// i8 GEMM: 256x256 block, BK=64, 8 waves (2x4) of 128x64,
// mfma_i32_16x16x64_i8, 1 barrier/K-tile, THREE 32KB LDS buffers (96KB —
// free: 64KB config already ran 1 block/CU per occupancy counters).
// Counted-vmcnt pipeline (T4): tile T stages T+2 -> buf[(T+2)%3] at tile
// start; end-of-T s_waitcnt vmcnt(4) retires exactly T+1's 4 stages (2
// tiles ~2850cyc of landing slack); lgkmcnt(0) drains T's reads (WAR for
// the stage at T+1 into buf[T%3]); single barrier.
// Read order (r12, best): bF[0..3]+aF[0..1] first, aF[2..7] interleaved
// with MFMA m-clusters. Swizzle phys_chunk = c ^ ((row>>1)&3) (0-conflict).
// ---------------------------------------------------------------------------
__global__ __launch_bounds__(512, 2) void gemm_i8(const int8_t* __restrict__ Aq,
                                                  const int8_t* __restrict__ Bq,
                                                  const float*  __restrict__ rowmul,
                                                  const float*  __restrict__ bias,
                                                  float*        __restrict__ C) {
    extern __shared__ char smem[];   // 3 x 32KB
    const int tid  = threadIdx.x;
    const int lane = tid & 63;
    const int wave = tid >> 6;
    const int wr   = wave >> 2;  // 0..1 -> A rows wr*128
    const int wc   = wave & 3;   // 0..3 -> B cols wc*64

    // grid: 32m x 16n = 512 blocks; per-XCD 8x8 region
    const int bid   = blockIdx.x;
    const int xcd   = bid & 7;
    const int local = bid >> 3;                      // 0..63
    const int m_idx = (xcd & 3) * 8 + (local & 7);   // 0..31
    const int n_idx = (xcd >> 2) * 8 + (local >> 3); // 0..15
    const size_t brow = (size_t)m_idx * 256;
    const size_t bcol = (size_t)n_idx * 256;

    // staging: thread t -> row r0=t>>2 (0..127), slot=t&3; source chunk
    // inverse-swizzled; dest linear t*16.
    const int r0 = tid >> 2;
    const int sc = ((tid & 3) ^ ((r0 >> 1) & 3)) << 4;
    const int8_t* aS0 = Aq + (size_t)(brow + r0)       * IN_F + sc;
    const int8_t* aS1 = Aq + (size_t)(brow + 128 + r0) * IN_F + sc;
    const int8_t* bS0 = Bq + (size_t)(bcol + r0)       * IN_F + sc;
    const int8_t* bS1 = Bq + (size_t)(bcol + 128 + r0) * IN_F + sc;
    const int dT = tid << 4;

    // ds_read (forward swizzle); frag rows are 64B so pcc independent of m,wr
    const int rrow = lane & 15;
    const int pcc  = (((lane >> 4)) ^ ((rrow >> 1) & 3)) << 4;
    const int aRd  = (wr * 128 + rrow) * 64 + pcc;           // + m*1024
    const int bRd  = 16384 + (wc * 64 + rrow) * 64 + pcc;    // + n*1024

    i32x4 acc[8][4];
#pragma unroll
    for (int m = 0; m < 8; ++m)
#pragma unroll
        for (int n = 0; n < 4; ++n) acc[m][n] = (i32x4){0, 0, 0, 0};

    i32x4 aF[8], bF[4];

#define SB() __builtin_amdgcn_sched_barrier(0)

    // CURB: this tile's buffer; STGB: buffer for T+2; AK: elem offset of T+2
    // VM: 4 -> vmcnt(4)+lgkm0; 0 -> vmcnt(0)+lgkm0; -1 -> none (last)
#define TILE(CURB, STGB, STGON, AK, VM) { \
    if (STGON) { \
        stg(aS0 + (AK), smem, (STGB) + dT); \
        stg(aS1 + (AK), smem, (STGB) + 8192 + dT); \
        stg(bS0 + (AK), smem, (STGB) + 16384 + dT); \
        stg(bS1 + (AK), smem, (STGB) + 24576 + dT); \
    } \
    _Pragma("unroll") \
    for (int n = 0; n < 4; ++n) \
        bF[n] = *(const i32x4*)(smem + (CURB) + bRd + n * 1024); \
    aF[0] = *(const i32x4*)(smem + (CURB) + aRd); \
    aF[1] = *(const i32x4*)(smem + (CURB) + aRd + 1024); \
    __builtin_amdgcn_s_setprio(1); \
    _Pragma("unroll") \
    for (int m = 0; m < 8; ++m) { \
        if (m < 6) \
            aF[m + 2] = *(const i32x4*)(smem + (CURB) + aRd + (m + 2) * 1024); \
        _Pragma("unroll") \
        for (int n = 0; n < 4; ++n) \
            acc[m][n] = __builtin_amdgcn_mfma_i32_16x16x64_i8( \
                aF[m], bF[n], acc[m][n], 0, 0, 0); \
    } \
    __builtin_amdgcn_s_setprio(0); \
    if ((VM) == 4) { \
        asm volatile("s_waitcnt vmcnt(4) lgkmcnt(0)" ::: "memory"); \
        SB(); __builtin_amdgcn_s_barrier(); SB(); \
    } else if ((VM) == 0) { \
        asm volatile("s_waitcnt vmcnt(0) lgkmcnt(0)" ::: "memory"); \
        SB(); __builtin_amdgcn_s_barrier(); SB(); \
    } \
}

    // prologue: stage T0 -> buf0, T1 -> buf1; vmcnt(4) lands T0; barrier
    stg(aS0, smem, dT);
    stg(aS1, smem, 8192 + dT);
    stg(bS0, smem, 16384 + dT);
    stg(bS1, smem, 24576 + dT);
    stg(aS0 + 64, smem, 32768 + dT);
    stg(aS1 + 64, smem, 32768 + 8192 + dT);
    stg(bS0 + 64, smem, 32768 + 16384 + dT);
    stg(bS1 + 64, smem, 32768 + 24576 + dT);
    asm volatile("s_waitcnt vmcnt(4)" ::: "memory");
    SB();
    __builtin_amdgcn_s_barrier();
    SB();

    // main loop: tiles 0..59 (20 x unroll-3, buffers 0/1/2), stage T+2
    for (int it = 0; it < 20; ++it) {
        TILE(0,     65536, 1, 128, 4);   // tile 3it   -> stages 3it+2 into buf2
        TILE(32768, 0,     1, 192, 4);   // tile 3it+1 -> stages 3it+3 into buf0
        TILE(65536, 32768, 1, 256, 4);   // tile 3it+2 -> stages 3it+4 into buf1
        aS0 += 192; aS1 += 192; bS0 += 192; bS1 += 192;
    }
    // peeled tail (pointers at kt=60): 60 stages 62, 61 stages 63, 62 drains
    TILE(0,     65536, 1, 128, 4);       // tile 60 -> stages 62 into buf2
    TILE(32768, 0,     1, 192, 4);       // tile 61 -> stages 63 into buf0
    TILE(65536, 0,     0, 0,   0);       // tile 62: vmcnt(0) lands 63
    TILE(0,     0,     0, 0,  -1);       // tile 63 (last, no waits)
#undef TILE
#undef SB

    // epilogue: C/D col = lane&15, row = (lane>>4)*4 + j (shape-determined)
    const int crow = (lane >> 4) << 2;
    const int ccol = lane & 15;
#pragma unroll
    for (int m = 0; m < 8; ++m) {
        const size_t rowbase = brow + wr * 128 + m * 16 + crow;
        float rm[4];
#pragma unroll
        for (int j = 0; j < 4; ++j) rm[j] = rowmul[rowbase + j];
#pragma unroll
        for (int n = 0; n < 4; ++n) {
            const size_t col = bcol + wc * 64 + n * 16 + ccol;
            const float bv = bias[col];
            float* cp = C + rowbase * OUT_F + col;
#pragma unroll
            for (int j = 0; j < 4; ++j)
                cp[(size_t)j * OUT_F] = (float)acc[m][n][j] * rm[j] + bv;
        }
    }
}

// ---------------------------------------------------------------------------
extern "C" void kernel_launch(void* const* d_in, const int* in_sizes, int n_in,
                              void* d_out, int out_size, void* d_ws, size_t ws_size,
                              hipStream_t stream) {
    const float* x    = (const float*)d_in[0];
    const float* hw   = (const float*)d_in[1];
    const float* hb   = (const float*)d_in[2];
    const float* xiW  = (const float*)d_in[3];
    const float* xiB  = (const float*)d_in[4];
    const int*   idxW = (const int*)d_in[5];
    const int*   idxB = (const int*)d_in[6];
    float* out = (float*)d_out;

    char* ws = (char*)d_ws;
    int8_t* Wq     = (int8_t*)ws;                                   // 16 MB
    int8_t* Xq     = (int8_t*)(ws + (size_t)16 * 1024 * 1024);      // 32 MB
    float*  rowmul = (float*)(ws + (size_t)48 * 1024 * 1024);       // 32 KB
    float*  bia    = (float*)(ws + (size_t)49 * 1024 * 1024);       // 16 KB

    (void)hipFuncSetAttribute((const void*)gemm_i8,
                              hipFuncAttributeMaxDynamicSharedMemorySize, 98304);

    prep<<<16400, 256, 0, stream>>>(hw, xiW, idxW, (u32x2*)Wq,
                                    x, (u32x4*)Xq, rowmul,
                                    hb, xiB, idxB, bia);
    // 32 m x 16 n = 512 blocks, 512 threads, 96KB dynamic LDS
    gemm_i8<<<512, 512, 98304, stream>>>(Xq, Wq, rowmul, bia, out);
}